// Round 1
// baseline (1537.300 us; speedup 1.0000x reference)
//
#include <hip/hip_runtime.h>
#include <cstdint>
#include <cstddef>

// ---------------- degree / normalization ----------------

__global__ void init_deg(float* __restrict__ deg, int N) {
  int i = blockIdx.x * 256 + threadIdx.x;
  if (i < N) deg[i] = 1.0f;  // self loop
}

__global__ void deg_accum(const int* __restrict__ cols, float* __restrict__ deg, int E) {
  int e = blockIdx.x * 256 + threadIdx.x;
  if (e < E) atomicAdd(&deg[cols[e]], 1.0f);
}

__global__ void make_dinv(float* __restrict__ deg, int N) {
  int i = blockIdx.x * 256 + threadIdx.x;
  if (i < N) deg[i] = rsqrtf(deg[i]);
}

// ---------------- dense GEMM: out[N,64] = h[N,K] @ W[K,64] ----------------
// 256 threads: 64 lanes = output feature j, 4 concurrent rows, 16 rows/block.
// W staged in LDS (K*64*4 B: 32KB for K=128, 16KB for K=64).

template <int K>
__global__ __launch_bounds__(256) void gemm64(const float* __restrict__ h,
                                              const float* __restrict__ W,
                                              float* __restrict__ out, int N) {
  __shared__ float sW[K * 64];
  for (int i = threadIdx.x; i < K * 64; i += 256) sW[i] = W[i];
  __syncthreads();
  int j = threadIdx.x & 63;
  int base = blockIdx.x * 16;
  for (int nl = (threadIdx.x >> 6); nl < 16; nl += 4) {
    int n = base + nl;
    if (n >= N) continue;
    const float* hr = h + (size_t)n * K;
    float s = 0.f;
#pragma unroll
    for (int k = 0; k < K; ++k) s = fmaf(hr[k], sW[k * 64 + j], s);
    out[(size_t)n * 64 + j] = s;
  }
}

// ---------------- edge scatter: agg[c] += HW[r] * dinv[r]*dinv[c] ----------------
// one wave (64 lanes) per edge; lane = feature. Fully coalesced gather + atomic.

__global__ __launch_bounds__(256) void scatter_edges(const float* __restrict__ HW,
                                                     const int* __restrict__ rows,
                                                     const int* __restrict__ cols,
                                                     const float* __restrict__ dinv,
                                                     float* __restrict__ agg, int E) {
  int e = blockIdx.x * 4 + (threadIdx.x >> 6);
  if (e >= E) return;
  int lane = threadIdx.x & 63;
  int r = rows[e];
  int c = cols[e];
  float nrm = dinv[r] * dinv[c];
  float v = HW[(size_t)r * 64 + lane] * nrm;
  atomicAdd(&agg[(size_t)c * 64 + lane], v);
}

// ---------------- self-loop + bias + ReLU (in place on agg) ----------------

__global__ __launch_bounds__(256) void finalize_relu(float* __restrict__ agg,
                                                     const float* __restrict__ HW,
                                                     const float* __restrict__ dinv,
                                                     const float* __restrict__ b, int N) {
  int i = blockIdx.x * 256 + threadIdx.x;
  int total = N * 64;
  if (i >= total) return;
  int n = i >> 6;
  int f = i & 63;
  float d = dinv[n];
  float v = agg[i] + HW[i] * d * d + b[f];
  agg[i] = v > 0.f ? v : 0.f;
}

// ---------------- MLP head: h[N,64] -> relu(h@lW1+lb1) -> sigmoid(@lW2+lb2) ----------------

__global__ __launch_bounds__(256) void head_kernel(const float* __restrict__ h,
                                                   const float* __restrict__ lW1,
                                                   const float* __restrict__ lb1,
                                                   const float* __restrict__ lW2,
                                                   const float* __restrict__ lb2,
                                                   float* __restrict__ p, int N) {
  int n = blockIdx.x * 256 + threadIdx.x;
  if (n >= N) return;
  float acc[8];
#pragma unroll
  for (int j = 0; j < 8; ++j) acc[j] = lb1[j];
  const float* hr = h + (size_t)n * 64;
#pragma unroll 8
  for (int k = 0; k < 64; ++k) {
    float v = hr[k];
#pragma unroll
    for (int j = 0; j < 8; ++j) acc[j] = fmaf(v, lW1[k * 8 + j], acc[j]);
  }
  float s = lb2[0];
#pragma unroll
  for (int j = 0; j < 8; ++j) {
    float a = acc[j] > 0.f ? acc[j] : 0.f;
    s = fmaf(a, lW2[j], s);
  }
  p[n] = 1.0f / (1.0f + expf(-s));
}

// ---------------- loss reductions ----------------

__global__ __launch_bounds__(256) void label_sum_kernel(const int* __restrict__ labels,
                                                        float* __restrict__ out, int N) {
  int i = blockIdx.x * 256 + threadIdx.x;
  float v = (i < N) ? (float)labels[i] : 0.f;
#pragma unroll
  for (int o = 32; o > 0; o >>= 1) v += __shfl_down(v, o);
  __shared__ float s[4];
  int lane = threadIdx.x & 63, w = threadIdx.x >> 6;
  if (lane == 0) s[w] = v;
  __syncthreads();
  if (threadIdx.x == 0) atomicAdd(out, s[0] + s[1] + s[2] + s[3]);
}

__global__ __launch_bounds__(256) void loss_kernel(const float* __restrict__ p,
                                                   const int* __restrict__ labels,
                                                   const float* __restrict__ pmsum,
                                                   float* __restrict__ loss, int N) {
  int i = blockIdx.x * 256 + threadIdx.x;
  float pm = *pmsum / (float)N;
  float v = 0.f;
  if (i < N) {
    float y = (float)labels[i];
    float w = y * (1.f - pm) + (1.f - y) * pm;
    float pc = fminf(fmaxf(p[i], 1e-7f), 1.f - 1e-7f);
    float bce = -(y * logf(pc) + (1.f - y) * logf(1.f - pc));
    v = w * bce / (float)N;
  }
#pragma unroll
  for (int o = 32; o > 0; o >>= 1) v += __shfl_down(v, o);
  __shared__ float s[4];
  int lane = threadIdx.x & 63, w = threadIdx.x >> 6;
  if (lane == 0) s[w] = v;
  __syncthreads();
  if (threadIdx.x == 0) atomicAdd(loss, s[0] + s[1] + s[2] + s[3]);
}

// ---------------- launch ----------------

extern "C" void kernel_launch(void* const* d_in, const int* in_sizes, int n_in,
                              void* d_out, int out_size, void* d_ws, size_t ws_size,
                              hipStream_t stream) {
  const float* x      = (const float*)d_in[0];
  const int*   ei     = (const int*)d_in[1];
  const int*   labels = (const int*)d_in[2];
  const float* W1 = (const float*)d_in[3];
  const float* b1 = (const float*)d_in[4];
  const float* W2 = (const float*)d_in[5];
  const float* b2 = (const float*)d_in[6];
  const float* W3 = (const float*)d_in[7];
  const float* b3 = (const float*)d_in[8];
  const float* lW1 = (const float*)d_in[9];
  const float* lb1 = (const float*)d_in[10];
  const float* lW2 = (const float*)d_in[11];
  const float* lb2 = (const float*)d_in[12];

  int N = in_sizes[2];            // labels: [N,1]
  int F = in_sizes[0] / N;        // 128
  int E = in_sizes[1] / 2;        // edge_index: [2,E]
  const int* rows = ei;           // sources
  const int* cols = ei + E;       // targets

  char* ws = (char*)d_ws;
  size_t nodeFeatBytes = (size_t)N * 64 * sizeof(float);
  float* A    = (float*)ws;                           // hW buffer
  float* B    = (float*)(ws + nodeFeatBytes);         // agg / hidden buffer
  float* dinv = (float*)(ws + 2 * nodeFeatBytes);     // N floats
  float* pmsum = dinv + N;                            // 1 float

  float* loss = (float*)d_out;
  float* p    = (float*)d_out + 1;

  // degree + normalization
  init_deg<<<(N + 255) / 256, 256, 0, stream>>>(dinv, N);
  deg_accum<<<(E + 255) / 256, 256, 0, stream>>>(cols, dinv, E);
  make_dinv<<<(N + 255) / 256, 256, 0, stream>>>(dinv, N);

  int gemmBlocks = (N + 15) / 16;
  int scatBlocks = (E + 3) / 4;
  int finBlocks  = (N * 64 + 255) / 256;

  // ---- layer 1 (K=128) ----
  gemm64<128><<<gemmBlocks, 256, 0, stream>>>(x, W1, A, N);
  hipMemsetAsync(B, 0, nodeFeatBytes, stream);
  scatter_edges<<<scatBlocks, 256, 0, stream>>>(A, rows, cols, dinv, B, E);
  finalize_relu<<<finBlocks, 256, 0, stream>>>(B, A, dinv, b1, N);

  // ---- layer 2 (K=64) ----
  gemm64<64><<<gemmBlocks, 256, 0, stream>>>(B, W2, A, N);
  hipMemsetAsync(B, 0, nodeFeatBytes, stream);
  scatter_edges<<<scatBlocks, 256, 0, stream>>>(A, rows, cols, dinv, B, E);
  finalize_relu<<<finBlocks, 256, 0, stream>>>(B, A, dinv, b2, N);

  // ---- layer 3 (K=64) ----
  gemm64<64><<<gemmBlocks, 256, 0, stream>>>(B, W3, A, N);
  hipMemsetAsync(B, 0, nodeFeatBytes, stream);
  scatter_edges<<<scatBlocks, 256, 0, stream>>>(A, rows, cols, dinv, B, E);
  finalize_relu<<<finBlocks, 256, 0, stream>>>(B, A, dinv, b3, N);

  // ---- head ----
  head_kernel<<<(N + 255) / 256, 256, 0, stream>>>(B, lW1, lb1, lW2, lb2, p, N);

  // ---- loss ----
  hipMemsetAsync(pmsum, 0, sizeof(float), stream);
  hipMemsetAsync(loss, 0, sizeof(float), stream);
  label_sum_kernel<<<(N + 255) / 256, 256, 0, stream>>>(labels, pmsum, N);
  loss_kernel<<<(N + 255) / 256, 256, 0, stream>>>(p, labels, pmsum, loss, N);
}

// Round 2
// 882.913 us; speedup vs baseline: 1.7412x; 1.7412x over previous
//
#include <hip/hip_runtime.h>
#include <cstdint>
#include <cstddef>

// ---------------- degree / normalization ----------------

__global__ void count_deg(const int* __restrict__ cols, int* __restrict__ deg, int E) {
  int e = blockIdx.x * 256 + threadIdx.x;
  if (e < E) atomicAdd(&deg[cols[e]], 1);
}

__global__ void make_dinv(const int* __restrict__ deg, float* __restrict__ dinv, int N) {
  int i = blockIdx.x * 256 + threadIdx.x;
  if (i < N) dinv[i] = rsqrtf((float)(deg[i] + 1));  // +1 self loop
}

// ---------------- prefix scan (3-phase) for CSR offsets ----------------

__global__ __launch_bounds__(256) void scan_partials(const int* __restrict__ deg,
                                                     int* __restrict__ partials, int N) {
  int i = blockIdx.x * 256 + threadIdx.x;
  int v = (i < N) ? deg[i] : 0;
#pragma unroll
  for (int o = 32; o > 0; o >>= 1) v += __shfl_down(v, o);
  __shared__ int s[4];
  if ((threadIdx.x & 63) == 0) s[threadIdx.x >> 6] = v;
  __syncthreads();
  if (threadIdx.x == 0) partials[blockIdx.x] = s[0] + s[1] + s[2] + s[3];
}

__global__ __launch_bounds__(256) void scan_block(int* __restrict__ partials, int nb) {
  __shared__ int tmp[256];
  __shared__ int carry;
  int tid = threadIdx.x;
  if (tid == 0) carry = 0;
  __syncthreads();
  for (int base = 0; base < nb; base += 256) {
    int i = base + tid;
    int v = (i < nb) ? partials[i] : 0;
    tmp[tid] = v;
    __syncthreads();
    int incl = v;
    for (int o = 1; o < 256; o <<= 1) {
      int t = (tid >= o) ? tmp[tid - o] : 0;
      __syncthreads();
      incl += t;
      tmp[tid] = incl;
      __syncthreads();
    }
    int total = tmp[255];
    int c = carry;
    if (i < nb) partials[i] = c + incl - v;  // exclusive
    __syncthreads();
    if (tid == 0) carry = c + total;
    __syncthreads();
  }
}

__global__ __launch_bounds__(256) void scan_final(const int* __restrict__ deg,
                                                  const int* __restrict__ partials,
                                                  int* __restrict__ offsets, int N) {
  __shared__ int tmp[256];
  int tid = threadIdx.x;
  int i = blockIdx.x * 256 + tid;
  int v = (i < N) ? deg[i] : 0;
  tmp[tid] = v;
  __syncthreads();
  int incl = v;
  for (int o = 1; o < 256; o <<= 1) {
    int t = (tid >= o) ? tmp[tid - o] : 0;
    __syncthreads();
    incl += t;
    tmp[tid] = incl;
    __syncthreads();
  }
  if (i < N) offsets[i] = partials[blockIdx.x] + incl - v;
}

// cursor[i] = offsets[i]; offsets[N] = E
__global__ void init_cursor(const int* __restrict__ offsets, int* __restrict__ cursor,
                            int* __restrict__ offsets_end, int N, int E) {
  int i = blockIdx.x * 256 + threadIdx.x;
  if (i < N) cursor[i] = offsets[i];
  if (i == 0) *offsets_end = E;
}

__global__ void fill_csr(const int* __restrict__ rows, const int* __restrict__ cols,
                         int* __restrict__ cursor, int* __restrict__ sorted_src, int E) {
  int e = blockIdx.x * 256 + threadIdx.x;
  if (e < E) {
    int c = cols[e];
    int pos = atomicAdd(&cursor[c], 1);
    sorted_src[pos] = rows[e];
  }
}

// ---------------- dense GEMM: out[N,64] = h[N,K] @ W[K,64] ----------------
// 256 threads: 64 lanes = feature j, each wave computes 4 rows (16 rows/block).

template <int K>
__global__ __launch_bounds__(256) void gemm64(const float* __restrict__ h,
                                              const float* __restrict__ W,
                                              float* __restrict__ out, int N) {
  __shared__ float sW[K * 64];
  for (int i = threadIdx.x; i < K * 64; i += 256) sW[i] = W[i];
  __syncthreads();
  int j = threadIdx.x & 63;
  int w = threadIdx.x >> 6;
  int n0 = blockIdx.x * 16 + w * 4;
  if (n0 + 3 < N) {
    const float4* h0 = (const float4*)(h + (size_t)(n0 + 0) * K);
    const float4* h1 = (const float4*)(h + (size_t)(n0 + 1) * K);
    const float4* h2 = (const float4*)(h + (size_t)(n0 + 2) * K);
    const float4* h3 = (const float4*)(h + (size_t)(n0 + 3) * K);
    float acc0 = 0.f, acc1 = 0.f, acc2 = 0.f, acc3 = 0.f;
#pragma unroll 4
    for (int k4 = 0; k4 < K / 4; ++k4) {
      float4 a = h0[k4], b = h1[k4], c = h2[k4], d = h3[k4];
      const float* wp = &sW[k4 * 4 * 64 + j];
      float w0 = wp[0], w1 = wp[64], w2 = wp[128], w3 = wp[192];
      acc0 = fmaf(a.x, w0, acc0); acc0 = fmaf(a.y, w1, acc0);
      acc0 = fmaf(a.z, w2, acc0); acc0 = fmaf(a.w, w3, acc0);
      acc1 = fmaf(b.x, w0, acc1); acc1 = fmaf(b.y, w1, acc1);
      acc1 = fmaf(b.z, w2, acc1); acc1 = fmaf(b.w, w3, acc1);
      acc2 = fmaf(c.x, w0, acc2); acc2 = fmaf(c.y, w1, acc2);
      acc2 = fmaf(c.z, w2, acc2); acc2 = fmaf(c.w, w3, acc2);
      acc3 = fmaf(d.x, w0, acc3); acc3 = fmaf(d.y, w1, acc3);
      acc3 = fmaf(d.z, w2, acc3); acc3 = fmaf(d.w, w3, acc3);
    }
    out[(size_t)(n0 + 0) * 64 + j] = acc0;
    out[(size_t)(n0 + 1) * 64 + j] = acc1;
    out[(size_t)(n0 + 2) * 64 + j] = acc2;
    out[(size_t)(n0 + 3) * 64 + j] = acc3;
  } else {
    for (int r = 0; r < 4; ++r) {
      int n = n0 + r;
      if (n >= N) break;
      const float* hr = h + (size_t)n * K;
      float s = 0.f;
      for (int k = 0; k < K; ++k) s = fmaf(hr[k], sW[k * 64 + j], s);
      out[(size_t)n * 64 + j] = s;
    }
  }
}

// ---------------- fused gather-aggregate + self loop + bias + ReLU ----------------
// one wave per node; lane = feature; edges of node c are contiguous in sorted_src.

__global__ __launch_bounds__(256) void aggregate(const float* __restrict__ HW,
                                                 const int* __restrict__ offsets,
                                                 const int* __restrict__ sorted_src,
                                                 const float* __restrict__ dinv,
                                                 const float* __restrict__ bias,
                                                 float* __restrict__ out, int N) {
  int c = blockIdx.x * 4 + (threadIdx.x >> 6);
  if (c >= N) return;
  int lane = threadIdx.x & 63;
  int s = offsets[c], e = offsets[c + 1];
  float acc = 0.f;
  for (int i = s; i < e; i += 64) {
    int nchunk = min(64, e - i);
    int idx = i + lane;
    int r = (idx < e) ? sorted_src[idx] : 0;
    float dr = (idx < e) ? dinv[r] : 0.f;
    for (int j = 0; j < nchunk; ++j) {
      int rj = __shfl(r, j);
      float drj = __shfl(dr, j);
      acc = fmaf(HW[(size_t)rj * 64 + lane], drj, acc);
    }
  }
  float dc = dinv[c];
  float self = HW[(size_t)c * 64 + lane] * dc;  // becomes HW[c]*dc*dc after *dc
  float v = fmaf(acc + self, dc, bias[lane]);
  out[(size_t)c * 64 + lane] = v > 0.f ? v : 0.f;
}

// ---------------- MLP head ----------------

__global__ __launch_bounds__(256) void head_kernel(const float* __restrict__ h,
                                                   const float* __restrict__ lW1,
                                                   const float* __restrict__ lb1,
                                                   const float* __restrict__ lW2,
                                                   const float* __restrict__ lb2,
                                                   float* __restrict__ p, int N) {
  int n = blockIdx.x * 256 + threadIdx.x;
  if (n >= N) return;
  float acc[8];
#pragma unroll
  for (int j = 0; j < 8; ++j) acc[j] = lb1[j];
  const float* hr = h + (size_t)n * 64;
#pragma unroll 8
  for (int k = 0; k < 64; ++k) {
    float v = hr[k];
#pragma unroll
    for (int j = 0; j < 8; ++j) acc[j] = fmaf(v, lW1[k * 8 + j], acc[j]);
  }
  float s = lb2[0];
#pragma unroll
  for (int j = 0; j < 8; ++j) {
    float a = acc[j] > 0.f ? acc[j] : 0.f;
    s = fmaf(a, lW2[j], s);
  }
  p[n] = 1.0f / (1.0f + expf(-s));
}

// ---------------- loss reductions ----------------

__global__ __launch_bounds__(256) void label_sum_kernel(const int* __restrict__ labels,
                                                        float* __restrict__ out, int N) {
  int i = blockIdx.x * 256 + threadIdx.x;
  float v = (i < N) ? (float)labels[i] : 0.f;
#pragma unroll
  for (int o = 32; o > 0; o >>= 1) v += __shfl_down(v, o);
  __shared__ float s[4];
  int lane = threadIdx.x & 63, w = threadIdx.x >> 6;
  if (lane == 0) s[w] = v;
  __syncthreads();
  if (threadIdx.x == 0) atomicAdd(out, s[0] + s[1] + s[2] + s[3]);
}

__global__ __launch_bounds__(256) void loss_kernel(const float* __restrict__ p,
                                                   const int* __restrict__ labels,
                                                   const float* __restrict__ pmsum,
                                                   float* __restrict__ loss, int N) {
  int i = blockIdx.x * 256 + threadIdx.x;
  float pm = *pmsum / (float)N;
  float v = 0.f;
  if (i < N) {
    float y = (float)labels[i];
    float w = y * (1.f - pm) + (1.f - y) * pm;
    float pc = fminf(fmaxf(p[i], 1e-7f), 1.f - 1e-7f);
    float bce = -(y * logf(pc) + (1.f - y) * logf(1.f - pc));
    v = w * bce / (float)N;
  }
#pragma unroll
  for (int o = 32; o > 0; o >>= 1) v += __shfl_down(v, o);
  __shared__ float s[4];
  int lane = threadIdx.x & 63, w = threadIdx.x >> 6;
  if (lane == 0) s[w] = v;
  __syncthreads();
  if (threadIdx.x == 0) atomicAdd(loss, s[0] + s[1] + s[2] + s[3]);
}

// ---------------- launch ----------------

extern "C" void kernel_launch(void* const* d_in, const int* in_sizes, int n_in,
                              void* d_out, int out_size, void* d_ws, size_t ws_size,
                              hipStream_t stream) {
  const float* x      = (const float*)d_in[0];
  const int*   ei     = (const int*)d_in[1];
  const int*   labels = (const int*)d_in[2];
  const float* W1 = (const float*)d_in[3];
  const float* b1 = (const float*)d_in[4];
  const float* W2 = (const float*)d_in[5];
  const float* b2 = (const float*)d_in[6];
  const float* W3 = (const float*)d_in[7];
  const float* b3 = (const float*)d_in[8];
  const float* lW1 = (const float*)d_in[9];
  const float* lb1 = (const float*)d_in[10];
  const float* lW2 = (const float*)d_in[11];
  const float* lb2 = (const float*)d_in[12];

  int N = in_sizes[2];            // labels: [N,1]
  int E = in_sizes[1] / 2;        // edge_index: [2,E]
  const int* rows = ei;           // sources
  const int* cols = ei + E;       // targets (aggregation)

  int nb = (N + 255) / 256;

  // workspace layout
  char* ws = (char*)d_ws;
  float* A       = (float*)ws;                 // hW          N*64
  float* B       = A + (size_t)N * 64;         // hidden      N*64
  float* dinv    = B + (size_t)N * 64;         // N
  int*   offsets = (int*)(dinv + N);           // N+1
  int*   deg     = offsets + N + 1;            // N (reused as cursor after scan)
  int*   sorted  = deg + N;                    // E
  int*   partials= sorted + E;                 // nb
  float* pmsum   = (float*)(partials + nb);    // 1

  float* loss = (float*)d_out;
  float* p    = (float*)d_out + 1;

  int gemmBlocks = (N + 15) / 16;
  int aggBlocks  = (N + 3) / 4;
  int nBlocks    = (N + 255) / 256;
  int eBlocks    = (E + 255) / 256;

  // ---- CSR build (once, reused for all 3 layers) ----
  hipMemsetAsync(deg, 0, (size_t)N * sizeof(int), stream);
  count_deg<<<eBlocks, 256, 0, stream>>>(cols, deg, E);
  make_dinv<<<nBlocks, 256, 0, stream>>>(deg, dinv, N);
  scan_partials<<<nb, 256, 0, stream>>>(deg, partials, N);
  scan_block<<<1, 256, 0, stream>>>(partials, nb);
  scan_final<<<nb, 256, 0, stream>>>(deg, partials, offsets, N);
  // deg buffer now dead -> reuse as cursor
  init_cursor<<<nBlocks, 256, 0, stream>>>(offsets, deg, offsets + N, N, E);
  fill_csr<<<eBlocks, 256, 0, stream>>>(rows, cols, deg, sorted, E);

  // ---- layer 1 (K=128) ----
  gemm64<128><<<gemmBlocks, 256, 0, stream>>>(x, W1, A, N);
  aggregate<<<aggBlocks, 256, 0, stream>>>(A, offsets, sorted, dinv, b1, B, N);

  // ---- layer 2 (K=64) ----
  gemm64<64><<<gemmBlocks, 256, 0, stream>>>(B, W2, A, N);
  aggregate<<<aggBlocks, 256, 0, stream>>>(A, offsets, sorted, dinv, b2, B, N);

  // ---- layer 3 (K=64) ----
  gemm64<64><<<gemmBlocks, 256, 0, stream>>>(B, W3, A, N);
  aggregate<<<aggBlocks, 256, 0, stream>>>(A, offsets, sorted, dinv, b3, B, N);

  // ---- head ----
  head_kernel<<<nBlocks, 256, 0, stream>>>(B, lW1, lb1, lW2, lb2, p, N);

  // ---- loss ----
  hipMemsetAsync(pmsum, 0, sizeof(float), stream);
  hipMemsetAsync(loss, 0, sizeof(float), stream);
  label_sum_kernel<<<nBlocks, 256, 0, stream>>>(labels, pmsum, N);
  loss_kernel<<<nBlocks, 256, 0, stream>>>(p, labels, pmsum, loss, N);
}

// Round 3
// 693.601 us; speedup vs baseline: 2.2164x; 1.2729x over previous
//
#include <hip/hip_runtime.h>
#include <cstdint>
#include <cstddef>

// ---------------- degree count (+ zero small scalars) ----------------

__global__ void count_deg(const int* __restrict__ cols, int* __restrict__ deg,
                          float* __restrict__ pmsum, float* __restrict__ loss, int E) {
  int e = blockIdx.x * 256 + threadIdx.x;
  if (blockIdx.x == 0 && threadIdx.x == 0) { *pmsum = 0.f; *loss = 0.f; }
  if (e < E) atomicAdd(&deg[cols[e]], 1);
}

// ---------------- prefix scan (3-phase) for CSR offsets ----------------

__global__ __launch_bounds__(256) void scan_partials(const int* __restrict__ deg,
                                                     int* __restrict__ partials, int N) {
  int i = blockIdx.x * 256 + threadIdx.x;
  int v = (i < N) ? deg[i] : 0;
#pragma unroll
  for (int o = 32; o > 0; o >>= 1) v += __shfl_down(v, o);
  __shared__ int s[4];
  if ((threadIdx.x & 63) == 0) s[threadIdx.x >> 6] = v;
  __syncthreads();
  if (threadIdx.x == 0) partials[blockIdx.x] = s[0] + s[1] + s[2] + s[3];
}

__global__ __launch_bounds__(256) void scan_block(int* __restrict__ partials, int nb) {
  __shared__ int tmp[256];
  __shared__ int carry;
  int tid = threadIdx.x;
  if (tid == 0) carry = 0;
  __syncthreads();
  for (int base = 0; base < nb; base += 256) {
    int i = base + tid;
    int v = (i < nb) ? partials[i] : 0;
    tmp[tid] = v;
    __syncthreads();
    int incl = v;
    for (int o = 1; o < 256; o <<= 1) {
      int t = (tid >= o) ? tmp[tid - o] : 0;
      __syncthreads();
      incl += t;
      tmp[tid] = incl;
      __syncthreads();
    }
    int total = tmp[255];
    int c = carry;
    if (i < nb) partials[i] = c + incl - v;  // exclusive
    __syncthreads();
    if (tid == 0) carry = c + total;
    __syncthreads();
  }
}

// exclusive offsets + cursor copy + dinv + offsets[N]=E, all in one pass
__global__ __launch_bounds__(256) void scan_final(const int* __restrict__ deg,
                                                  const int* __restrict__ partials,
                                                  int* __restrict__ offsets,
                                                  int* __restrict__ cursor,
                                                  float* __restrict__ dinv,
                                                  int N, int E) {
  __shared__ int tmp[256];
  int tid = threadIdx.x;
  int i = blockIdx.x * 256 + tid;
  int v = (i < N) ? deg[i] : 0;
  tmp[tid] = v;
  __syncthreads();
  int incl = v;
  for (int o = 1; o < 256; o <<= 1) {
    int t = (tid >= o) ? tmp[tid - o] : 0;
    __syncthreads();
    incl += t;
    tmp[tid] = incl;
    __syncthreads();
  }
  if (i < N) {
    int ex = partials[blockIdx.x] + incl - v;
    offsets[i] = ex;
    cursor[i] = ex;
    dinv[i] = rsqrtf((float)(v + 1));  // +1 self loop
    if (i == N - 1) offsets[N] = E;
  }
}

// ---------------- CSR fill, restricted node range (L2-resident scatter) ----------------

__global__ void fill_csr_range(const int* __restrict__ rows, const int* __restrict__ cols,
                               int* __restrict__ cursor, int* __restrict__ sorted_src,
                               int E, int lo, int hi) {
  int e = blockIdx.x * 256 + threadIdx.x;
  if (e < E) {
    int c = cols[e];
    if (c >= lo && c < hi) {
      int pos = atomicAdd(&cursor[c], 1);
      sorted_src[pos] = rows[e];
    }
  }
}

// ---------------- dense GEMM: out[N,64] = (h[N,K] @ W[K,64]) * dinv[n] ----------------
// 256 threads = 4 waves; wave computes 8 rows (32 rows/block); lane = out feature.

template <int K>
__global__ __launch_bounds__(256) void gemm64(const float* __restrict__ h,
                                              const float* __restrict__ W,
                                              const float* __restrict__ dinv,
                                              float* __restrict__ out, int N) {
  __shared__ float sW[K * 64];
  for (int i = threadIdx.x; i < K * 64; i += 256) sW[i] = W[i];
  __syncthreads();
  int j = threadIdx.x & 63;
  int w = threadIdx.x >> 6;
  int n0 = blockIdx.x * 32 + w * 8;
  float acc[8] = {0.f, 0.f, 0.f, 0.f, 0.f, 0.f, 0.f, 0.f};
  if (n0 + 7 < N) {
    const float4* hp0 = (const float4*)(h + (size_t)(n0 + 0) * K);
    const float4* hp1 = (const float4*)(h + (size_t)(n0 + 1) * K);
    const float4* hp2 = (const float4*)(h + (size_t)(n0 + 2) * K);
    const float4* hp3 = (const float4*)(h + (size_t)(n0 + 3) * K);
    const float4* hp4 = (const float4*)(h + (size_t)(n0 + 4) * K);
    const float4* hp5 = (const float4*)(h + (size_t)(n0 + 5) * K);
    const float4* hp6 = (const float4*)(h + (size_t)(n0 + 6) * K);
    const float4* hp7 = (const float4*)(h + (size_t)(n0 + 7) * K);
#pragma unroll 2
    for (int k4 = 0; k4 < K / 4; ++k4) {
      float4 a0 = hp0[k4], a1 = hp1[k4], a2 = hp2[k4], a3 = hp3[k4];
      float4 a4 = hp4[k4], a5 = hp5[k4], a6 = hp6[k4], a7 = hp7[k4];
      const float* wp = &sW[k4 * 4 * 64 + j];
      float w0 = wp[0], w1 = wp[64], w2 = wp[128], w3 = wp[192];
      acc[0] = fmaf(a0.x, w0, acc[0]); acc[0] = fmaf(a0.y, w1, acc[0]);
      acc[0] = fmaf(a0.z, w2, acc[0]); acc[0] = fmaf(a0.w, w3, acc[0]);
      acc[1] = fmaf(a1.x, w0, acc[1]); acc[1] = fmaf(a1.y, w1, acc[1]);
      acc[1] = fmaf(a1.z, w2, acc[1]); acc[1] = fmaf(a1.w, w3, acc[1]);
      acc[2] = fmaf(a2.x, w0, acc[2]); acc[2] = fmaf(a2.y, w1, acc[2]);
      acc[2] = fmaf(a2.z, w2, acc[2]); acc[2] = fmaf(a2.w, w3, acc[2]);
      acc[3] = fmaf(a3.x, w0, acc[3]); acc[3] = fmaf(a3.y, w1, acc[3]);
      acc[3] = fmaf(a3.z, w2, acc[3]); acc[3] = fmaf(a3.w, w3, acc[3]);
      acc[4] = fmaf(a4.x, w0, acc[4]); acc[4] = fmaf(a4.y, w1, acc[4]);
      acc[4] = fmaf(a4.z, w2, acc[4]); acc[4] = fmaf(a4.w, w3, acc[4]);
      acc[5] = fmaf(a5.x, w0, acc[5]); acc[5] = fmaf(a5.y, w1, acc[5]);
      acc[5] = fmaf(a5.z, w2, acc[5]); acc[5] = fmaf(a5.w, w3, acc[5]);
      acc[6] = fmaf(a6.x, w0, acc[6]); acc[6] = fmaf(a6.y, w1, acc[6]);
      acc[6] = fmaf(a6.z, w2, acc[6]); acc[6] = fmaf(a6.w, w3, acc[6]);
      acc[7] = fmaf(a7.x, w0, acc[7]); acc[7] = fmaf(a7.y, w1, acc[7]);
      acc[7] = fmaf(a7.z, w2, acc[7]); acc[7] = fmaf(a7.w, w3, acc[7]);
    }
#pragma unroll
    for (int r = 0; r < 8; ++r)
      out[(size_t)(n0 + r) * 64 + j] = acc[r] * dinv[n0 + r];
  } else {
    for (int r = 0; r < 8; ++r) {
      int n = n0 + r;
      if (n >= N) break;
      const float* hr = h + (size_t)n * K;
      float s = 0.f;
      for (int k = 0; k < K; ++k) s = fmaf(hr[k], sW[k * 64 + j], s);
      out[(size_t)n * 64 + j] = s * dinv[n];
    }
  }
}

// ---------------- fused gather-aggregate + self loop + bias + ReLU ----------------
// one wave per node; 4 lane-groups of 16; one dwordx4 load covers 4 edge rows.
// A = (h@W)*dinv ; out[c] = relu((sum_r A[r] + A[c]) * dinv[c] + b)

__global__ __launch_bounds__(256) void aggregate(const float* __restrict__ A,
                                                 const int* __restrict__ offsets,
                                                 const int* __restrict__ sorted_src,
                                                 const float* __restrict__ dinv,
                                                 const float* __restrict__ bias,
                                                 float* __restrict__ out, int N) {
  int c = blockIdx.x * 4 + (threadIdx.x >> 6);
  if (c >= N) return;
  int lane = threadIdx.x & 63;
  int g = lane >> 4;       // edge sub-slot 0..3
  int fi = lane & 15;      // 16B chunk of the 256B row
  int s = offsets[c], e = offsets[c + 1];
  float4 acc = {0.f, 0.f, 0.f, 0.f};
  for (int base = s; base < e; base += 64) {
    int idx = base + lane;
    int r = (idx < e) ? sorted_src[idx] : 0;
    int cnt = e - base; if (cnt > 64) cnt = 64;
    int steps = (cnt + 3) >> 2;
    for (int t = 0; t < steps; ++t) {
      int jj = t * 4 + g;
      int rj = __shfl(r, jj);
      if (jj < cnt) {
        float4 v = ((const float4*)(A + (size_t)rj * 64))[fi];
        acc.x += v.x; acc.y += v.y; acc.z += v.z; acc.w += v.w;
      }
    }
  }
  // reduce partial sums across the 4 groups
  acc.x += __shfl_xor(acc.x, 16); acc.y += __shfl_xor(acc.y, 16);
  acc.z += __shfl_xor(acc.z, 16); acc.w += __shfl_xor(acc.w, 16);
  acc.x += __shfl_xor(acc.x, 32); acc.y += __shfl_xor(acc.y, 32);
  acc.z += __shfl_xor(acc.z, 32); acc.w += __shfl_xor(acc.w, 32);
  float dc = dinv[c];
  float4 sv = ((const float4*)(A + (size_t)c * 64))[fi];
  float4 b4 = ((const float4*)bias)[fi];
  float4 o;
  o.x = fmaf(acc.x + sv.x, dc, b4.x);
  o.y = fmaf(acc.y + sv.y, dc, b4.y);
  o.z = fmaf(acc.z + sv.z, dc, b4.z);
  o.w = fmaf(acc.w + sv.w, dc, b4.w);
  o.x = o.x > 0.f ? o.x : 0.f;
  o.y = o.y > 0.f ? o.y : 0.f;
  o.z = o.z > 0.f ? o.z : 0.f;
  o.w = o.w > 0.f ? o.w : 0.f;
  if (g == 0) ((float4*)(out + (size_t)c * 64))[fi] = o;
}

// ---------------- label mean partial sum ----------------

__global__ __launch_bounds__(256) void label_sum_kernel(const int* __restrict__ labels,
                                                        float* __restrict__ out, int N) {
  int i = blockIdx.x * 256 + threadIdx.x;
  float v = (i < N) ? (float)labels[i] : 0.f;
#pragma unroll
  for (int o = 32; o > 0; o >>= 1) v += __shfl_down(v, o);
  __shared__ float s[4];
  int lane = threadIdx.x & 63, w = threadIdx.x >> 6;
  if (lane == 0) s[w] = v;
  __syncthreads();
  if (threadIdx.x == 0) atomicAdd(out, s[0] + s[1] + s[2] + s[3]);
}

// ---------------- fused MLP head + sigmoid + weighted BCE loss ----------------

__global__ __launch_bounds__(256) void head_loss_kernel(const float* __restrict__ h,
                                                        const float* __restrict__ lW1,
                                                        const float* __restrict__ lb1,
                                                        const float* __restrict__ lW2,
                                                        const float* __restrict__ lb2,
                                                        const int* __restrict__ labels,
                                                        const float* __restrict__ pmsum,
                                                        float* __restrict__ p,
                                                        float* __restrict__ loss, int N) {
  int n = blockIdx.x * 256 + threadIdx.x;
  float contrib = 0.f;
  if (n < N) {
    float acc[8];
#pragma unroll
    for (int j = 0; j < 8; ++j) acc[j] = lb1[j];
    const float* hr = h + (size_t)n * 64;
#pragma unroll 8
    for (int k = 0; k < 64; ++k) {
      float v = hr[k];
#pragma unroll
      for (int j = 0; j < 8; ++j) acc[j] = fmaf(v, lW1[k * 8 + j], acc[j]);
    }
    float s = lb2[0];
#pragma unroll
    for (int j = 0; j < 8; ++j) {
      float a = acc[j] > 0.f ? acc[j] : 0.f;
      s = fmaf(a, lW2[j], s);
    }
    float pv = 1.0f / (1.0f + expf(-s));
    p[n] = pv;
    float pm = *pmsum / (float)N;
    float y = (float)labels[n];
    float w = y * (1.f - pm) + (1.f - y) * pm;
    float pc = fminf(fmaxf(pv, 1e-7f), 1.f - 1e-7f);
    float bce = -(y * logf(pc) + (1.f - y) * logf(1.f - pc));
    contrib = w * bce / (float)N;
  }
#pragma unroll
  for (int o = 32; o > 0; o >>= 1) contrib += __shfl_down(contrib, o);
  __shared__ float sh[4];
  int lane = threadIdx.x & 63, w = threadIdx.x >> 6;
  if (lane == 0) sh[w] = contrib;
  __syncthreads();
  if (threadIdx.x == 0) atomicAdd(loss, sh[0] + sh[1] + sh[2] + sh[3]);
}

// ---------------- launch ----------------

extern "C" void kernel_launch(void* const* d_in, const int* in_sizes, int n_in,
                              void* d_out, int out_size, void* d_ws, size_t ws_size,
                              hipStream_t stream) {
  const float* x      = (const float*)d_in[0];
  const int*   ei     = (const int*)d_in[1];
  const int*   labels = (const int*)d_in[2];
  const float* W1 = (const float*)d_in[3];
  const float* b1 = (const float*)d_in[4];
  const float* W2 = (const float*)d_in[5];
  const float* b2 = (const float*)d_in[6];
  const float* W3 = (const float*)d_in[7];
  const float* b3 = (const float*)d_in[8];
  const float* lW1 = (const float*)d_in[9];
  const float* lb1 = (const float*)d_in[10];
  const float* lW2 = (const float*)d_in[11];
  const float* lb2 = (const float*)d_in[12];

  int N = in_sizes[2];            // labels: [N,1]
  int E = in_sizes[1] / 2;        // edge_index: [2,E]
  const int* rows = ei;           // sources
  const int* cols = ei + E;       // targets (aggregation)

  int nb = (N + 255) / 256;

  // workspace layout
  char* ws = (char*)d_ws;
  float* A        = (float*)ws;                 // (h@W)*dinv   N*64
  float* B        = A + (size_t)N * 64;         // hidden       N*64
  float* dinv     = B + (size_t)N * 64;         // N
  int*   offsets  = (int*)(dinv + N);           // N+1
  int*   deg      = offsets + N + 1;            // N
  int*   cursor   = deg + N;                    // N
  int*   sorted   = cursor + N;                 // E
  int*   partials = sorted + E;                 // nb
  float* pmsum    = (float*)(partials + nb);    // 1

  float* loss = (float*)d_out;
  float* p    = (float*)d_out + 1;

  int gemmBlocks = (N + 31) / 32;
  int aggBlocks  = (N + 3) / 4;
  int eBlocks    = (E + 255) / 256;

  // ---- CSR build (once, reused for all 3 layers) ----
  hipMemsetAsync(deg, 0, (size_t)N * sizeof(int), stream);
  count_deg<<<eBlocks, 256, 0, stream>>>(cols, deg, pmsum, loss, E);
  label_sum_kernel<<<nb, 256, 0, stream>>>(labels, pmsum, N);
  scan_partials<<<nb, 256, 0, stream>>>(deg, partials, N);
  scan_block<<<1, 256, 0, stream>>>(partials, nb);
  scan_final<<<nb, 256, 0, stream>>>(deg, partials, offsets, cursor, dinv, N, E);
  // 4 node-range passes: active scatter region ~E/4*4B = 1.6 MB, L2-resident
  for (int pass = 0; pass < 4; ++pass) {
    int lo = (int)((long)N * pass / 4);
    int hi = (int)((long)N * (pass + 1) / 4);
    fill_csr_range<<<eBlocks, 256, 0, stream>>>(rows, cols, cursor, sorted, E, lo, hi);
  }

  // ---- layer 1 (K=128) ----
  gemm64<128><<<gemmBlocks, 256, 0, stream>>>(x, W1, dinv, A, N);
  aggregate<<<aggBlocks, 256, 0, stream>>>(A, offsets, sorted, dinv, b1, B, N);

  // ---- layer 2 (K=64) ----
  gemm64<64><<<gemmBlocks, 256, 0, stream>>>(B, W2, dinv, A, N);
  aggregate<<<aggBlocks, 256, 0, stream>>>(A, offsets, sorted, dinv, b2, B, N);

  // ---- layer 3 (K=64) ----
  gemm64<64><<<gemmBlocks, 256, 0, stream>>>(B, W3, dinv, A, N);
  aggregate<<<aggBlocks, 256, 0, stream>>>(A, offsets, sorted, dinv, b3, B, N);

  // ---- head + loss (pmsum ready since label_sum ran earlier) ----
  head_loss_kernel<<<nb, 256, 0, stream>>>(B, lW1, lb1, lW2, lb2, labels, pmsum, p, loss, N);
}

// Round 4
// 484.103 us; speedup vs baseline: 3.1756x; 1.4328x over previous
//
#include <hip/hip_runtime.h>
#include <cstdint>
#include <cstddef>

typedef __attribute__((ext_vector_type(8))) short short8;
typedef __attribute__((ext_vector_type(4))) float f32x4;

__device__ inline unsigned short f2bf(float f) {
  union { float f; unsigned int u; } x; x.f = f;
  unsigned int r = x.u + 0x7FFFu + ((x.u >> 16) & 1u);  // round-to-nearest-even
  return (unsigned short)(r >> 16);
}
__device__ inline float bf2f(unsigned short s) {
  union { unsigned int u; float f; } x; x.u = ((unsigned int)s) << 16;
  return x.f;
}

// ---------------- W -> W^T bf16 (tiny, once per call) ----------------

__global__ void prep_wt(const float* __restrict__ W1, const float* __restrict__ W2,
                        const float* __restrict__ W3, unsigned short* __restrict__ Wt1,
                        unsigned short* __restrict__ Wt2, unsigned short* __restrict__ Wt3) {
  const float* W; unsigned short* Wt; int K;
  if (blockIdx.x == 0)      { W = W1; Wt = Wt1; K = 128; }
  else if (blockIdx.x == 1) { W = W2; Wt = Wt2; K = 64; }
  else                      { W = W3; Wt = Wt3; K = 64; }
  int total = K * 64;
  for (int i = threadIdx.x; i < total; i += 256) {
    int n = i / K, k = i - n * K;      // Wt[n][k] = W[k][n]
    Wt[i] = f2bf(W[k * 64 + n]);
  }
}

// ---------------- degree count (+ zero small scalars) ----------------

__global__ void count_deg(const int* __restrict__ cols, int* __restrict__ deg,
                          float* __restrict__ pmsum, float* __restrict__ loss, int E) {
  int e = blockIdx.x * 256 + threadIdx.x;
  if (blockIdx.x == 0 && threadIdx.x == 0) { *pmsum = 0.f; *loss = 0.f; }
  if (e < E) atomicAdd(&deg[cols[e]], 1);
}

// ---------------- prefix scan (3-phase) for CSR offsets ----------------

__global__ __launch_bounds__(256) void scan_partials(const int* __restrict__ deg,
                                                     int* __restrict__ partials, int N) {
  int i = blockIdx.x * 256 + threadIdx.x;
  int v = (i < N) ? deg[i] : 0;
#pragma unroll
  for (int o = 32; o > 0; o >>= 1) v += __shfl_down(v, o);
  __shared__ int s[4];
  if ((threadIdx.x & 63) == 0) s[threadIdx.x >> 6] = v;
  __syncthreads();
  if (threadIdx.x == 0) partials[blockIdx.x] = s[0] + s[1] + s[2] + s[3];
}

__global__ __launch_bounds__(256) void scan_block(int* __restrict__ partials, int nb) {
  __shared__ int tmp[256];
  __shared__ int carry;
  int tid = threadIdx.x;
  if (tid == 0) carry = 0;
  __syncthreads();
  for (int base = 0; base < nb; base += 256) {
    int i = base + tid;
    int v = (i < nb) ? partials[i] : 0;
    tmp[tid] = v;
    __syncthreads();
    int incl = v;
    for (int o = 1; o < 256; o <<= 1) {
      int t = (tid >= o) ? tmp[tid - o] : 0;
      __syncthreads();
      incl += t;
      tmp[tid] = incl;
      __syncthreads();
    }
    int total = tmp[255];
    int c = carry;
    if (i < nb) partials[i] = c + incl - v;  // exclusive
    __syncthreads();
    if (tid == 0) carry = c + total;
    __syncthreads();
  }
}

__global__ __launch_bounds__(256) void scan_final(const int* __restrict__ deg,
                                                  const int* __restrict__ partials,
                                                  int* __restrict__ offsets,
                                                  int* __restrict__ cursor,
                                                  float* __restrict__ dinv,
                                                  int N, int E) {
  __shared__ int tmp[256];
  int tid = threadIdx.x;
  int i = blockIdx.x * 256 + tid;
  int v = (i < N) ? deg[i] : 0;
  tmp[tid] = v;
  __syncthreads();
  int incl = v;
  for (int o = 1; o < 256; o <<= 1) {
    int t = (tid >= o) ? tmp[tid - o] : 0;
    __syncthreads();
    incl += t;
    tmp[tid] = incl;
    __syncthreads();
  }
  if (i < N) {
    int ex = partials[blockIdx.x] + incl - v;
    offsets[i] = ex;
    cursor[i] = ex;
    dinv[i] = rsqrtf((float)(v + 1));  // +1 self loop
    if (i == N - 1) offsets[N] = E;
  }
}

// ---------------- CSR fill, restricted node range (L2-resident scatter) ----------------

__global__ void fill_csr_range(const int* __restrict__ rows, const int* __restrict__ cols,
                               int* __restrict__ cursor, int* __restrict__ sorted_src,
                               int E, int lo, int hi) {
  int e = blockIdx.x * 256 + threadIdx.x;
  if (e < E) {
    int c = cols[e];
    if (c >= lo && c < hi) {
      int pos = atomicAdd(&cursor[c], 1);
      sorted_src[pos] = rows[e];
    }
  }
}

// ---------------- MFMA GEMM: out_bf16[N,64] = (h[N,K] @ W[K,64]) * dinv[n] ----------------
// 256 thr = 4 waves; block = 64 rows; wave = 16 rows x 64 cols (4 n-tiles).
// A-frag: lane holds h[m0 + (lane&15)][kc*32 + (lane>>4)*8 + j], j=0..7 (16B contiguous).
// B-frag: lane holds Wt[t*16 + (lane&15)][kc*32 + (lane>>4)*8 + j] (Wt = W^T, bf16).
// D: row = (lane>>4)*4 + reg, col = lane&15 (m89-verified). LDS transpose for coalesced store.

template <int K, bool F32IN>
__global__ __launch_bounds__(256) void mfma_gemm(const void* __restrict__ hv,
                                                 const unsigned short* __restrict__ Wt,
                                                 const float* __restrict__ dinv,
                                                 unsigned short* __restrict__ out, int N) {
  __shared__ unsigned short tile[4][16 * 68];  // +4 pad per row: conflict-free epilogue
  int w = threadIdx.x >> 6, lane = threadIdx.x & 63;
  int m = lane & 15, quad = lane >> 4;
  int m0 = blockIdx.x * 64 + w * 16;
  int rowA = m0 + m;
  bool rowOK = rowA < N;
  f32x4 acc[4] = {{0.f,0.f,0.f,0.f},{0.f,0.f,0.f,0.f},{0.f,0.f,0.f,0.f},{0.f,0.f,0.f,0.f}};
#pragma unroll
  for (int kc = 0; kc < K / 32; ++kc) {
    short8 a = {0, 0, 0, 0, 0, 0, 0, 0};
    if (rowOK) {
      if (F32IN) {
        const float* hp = (const float*)hv + (size_t)rowA * K + kc * 32 + quad * 8;
        float4 p0 = ((const float4*)hp)[0];
        float4 p1 = ((const float4*)hp)[1];
        a[0] = (short)f2bf(p0.x); a[1] = (short)f2bf(p0.y);
        a[2] = (short)f2bf(p0.z); a[3] = (short)f2bf(p0.w);
        a[4] = (short)f2bf(p1.x); a[5] = (short)f2bf(p1.y);
        a[6] = (short)f2bf(p1.z); a[7] = (short)f2bf(p1.w);
      } else {
        a = *(const short8*)((const unsigned short*)hv + (size_t)rowA * K + kc * 32 + quad * 8);
      }
    }
#pragma unroll
    for (int t = 0; t < 4; ++t) {
      short8 b = *(const short8*)(Wt + (size_t)(t * 16 + m) * K + kc * 32 + quad * 8);
      acc[t] = __builtin_amdgcn_mfma_f32_16x16x32_bf16(a, b, acc[t], 0, 0, 0);
    }
  }
  // epilogue: scale by dinv, bf16, LDS transpose, coalesced global store
  unsigned short* tw = tile[w];
#pragma unroll
  for (int r = 0; r < 4; ++r) {
    int row = quad * 4 + r;
    int gr = m0 + row;
    float dv = dinv[gr < N ? gr : 0];
#pragma unroll
    for (int t = 0; t < 4; ++t)
      tw[row * 68 + t * 16 + m] = f2bf(acc[t][r] * dv);
  }
  // wave-private tile: no barrier needed (compiler inserts lgkmcnt wait)
#pragma unroll
  for (int p = 0; p < 4; ++p) {
    int row = p * 4 + (lane >> 4);
    int ch = lane & 15;  // 4-ushort (8B) chunk
    int gr = m0 + row;
    if (gr < N) {
      uint2 v = *(const uint2*)(tw + row * 68 + ch * 4);
      *(uint2*)(out + (size_t)gr * 64 + ch * 4) = v;
    }
  }
}

// ---------------- fused gather-aggregate + self loop + bias + ReLU (bf16 in/out) ----------------
// one wave per node; 8 lane-groups of 8; one 16B load covers 1/8 of a 128B bf16 row,
// 8 edge rows in flight per wave instruction. fp32 accumulate.

__global__ __launch_bounds__(256) void aggregate(const unsigned short* __restrict__ A,
                                                 const int* __restrict__ offsets,
                                                 const int* __restrict__ sorted_src,
                                                 const float* __restrict__ dinv,
                                                 const float* __restrict__ bias,
                                                 unsigned short* __restrict__ out, int N) {
  int c = blockIdx.x * 4 + (threadIdx.x >> 6);
  if (c >= N) return;
  int lane = threadIdx.x & 63;
  int g = lane >> 3;   // edge sub-slot 0..7
  int fi = lane & 7;   // 16B chunk of the 128B row
  int s = offsets[c], e = offsets[c + 1];
  float acc[8] = {0.f, 0.f, 0.f, 0.f, 0.f, 0.f, 0.f, 0.f};
  for (int base = s; base < e; base += 64) {
    int idx = base + lane;
    int r = (idx < e) ? sorted_src[idx] : 0;
    int cnt = e - base; if (cnt > 64) cnt = 64;
    int steps = (cnt + 7) >> 3;
    for (int t = 0; t < steps; ++t) {
      int jj = t * 8 + g;
      int rj = __shfl(r, jj);
      if (jj < cnt) {
        short8 v = *(const short8*)(A + (size_t)rj * 64 + fi * 8);
#pragma unroll
        for (int q = 0; q < 8; ++q) acc[q] += bf2f((unsigned short)v[q]);
      }
    }
  }
#pragma unroll
  for (int q = 0; q < 8; ++q) {
    acc[q] += __shfl_xor(acc[q], 8);
    acc[q] += __shfl_xor(acc[q], 16);
    acc[q] += __shfl_xor(acc[q], 32);
  }
  if (g == 0) {
    float dc = dinv[c];
    short8 sv = *(const short8*)(A + (size_t)c * 64 + fi * 8);
    short8 ov;
#pragma unroll
    for (int q = 0; q < 8; ++q) {
      float v = fmaf(acc[q] + bf2f((unsigned short)sv[q]), dc, bias[fi * 8 + q]);
      ov[q] = (short)f2bf(v > 0.f ? v : 0.f);
    }
    *(short8*)(out + (size_t)c * 64 + fi * 8) = ov;
  }
}

// ---------------- label mean partial sum ----------------

__global__ __launch_bounds__(256) void label_sum_kernel(const int* __restrict__ labels,
                                                        float* __restrict__ out, int N) {
  int i = blockIdx.x * 256 + threadIdx.x;
  float v = (i < N) ? (float)labels[i] : 0.f;
#pragma unroll
  for (int o = 32; o > 0; o >>= 1) v += __shfl_down(v, o);
  __shared__ float s[4];
  int lane = threadIdx.x & 63, w = threadIdx.x >> 6;
  if (lane == 0) s[w] = v;
  __syncthreads();
  if (threadIdx.x == 0) atomicAdd(out, s[0] + s[1] + s[2] + s[3]);
}

// ---------------- fused MLP head + sigmoid + weighted BCE loss (bf16 h) ----------------

__global__ __launch_bounds__(256) void head_loss_kernel(const unsigned short* __restrict__ h,
                                                        const float* __restrict__ lW1,
                                                        const float* __restrict__ lb1,
                                                        const float* __restrict__ lW2,
                                                        const float* __restrict__ lb2,
                                                        const int* __restrict__ labels,
                                                        const float* __restrict__ pmsum,
                                                        float* __restrict__ p,
                                                        float* __restrict__ loss, int N) {
  int n = blockIdx.x * 256 + threadIdx.x;
  float contrib = 0.f;
  if (n < N) {
    float acc[8];
#pragma unroll
    for (int j = 0; j < 8; ++j) acc[j] = lb1[j];
    const unsigned short* hr = h + (size_t)n * 64;
#pragma unroll
    for (int ch = 0; ch < 8; ++ch) {
      short8 hv8 = ((const short8*)hr)[ch];
#pragma unroll
      for (int q = 0; q < 8; ++q) {
        float v = bf2f((unsigned short)hv8[q]);
        int k = ch * 8 + q;
#pragma unroll
        for (int j = 0; j < 8; ++j) acc[j] = fmaf(v, lW1[k * 8 + j], acc[j]);
      }
    }
    float s = lb2[0];
#pragma unroll
    for (int j = 0; j < 8; ++j) {
      float a = acc[j] > 0.f ? acc[j] : 0.f;
      s = fmaf(a, lW2[j], s);
    }
    float pv = 1.0f / (1.0f + expf(-s));
    p[n] = pv;
    float pm = *pmsum / (float)N;
    float y = (float)labels[n];
    float w = y * (1.f - pm) + (1.f - y) * pm;
    float pc = fminf(fmaxf(pv, 1e-7f), 1.f - 1e-7f);
    float bce = -(y * logf(pc) + (1.f - y) * logf(1.f - pc));
    contrib = w * bce / (float)N;
  }
#pragma unroll
  for (int o = 32; o > 0; o >>= 1) contrib += __shfl_down(contrib, o);
  __shared__ float sh[4];
  int lane = threadIdx.x & 63, w = threadIdx.x >> 6;
  if (lane == 0) sh[w] = contrib;
  __syncthreads();
  if (threadIdx.x == 0) atomicAdd(loss, sh[0] + sh[1] + sh[2] + sh[3]);
}

// ---------------- launch ----------------

extern "C" void kernel_launch(void* const* d_in, const int* in_sizes, int n_in,
                              void* d_out, int out_size, void* d_ws, size_t ws_size,
                              hipStream_t stream) {
  const float* x      = (const float*)d_in[0];
  const int*   ei     = (const int*)d_in[1];
  const int*   labels = (const int*)d_in[2];
  const float* W1 = (const float*)d_in[3];
  const float* b1 = (const float*)d_in[4];
  const float* W2 = (const float*)d_in[5];
  const float* b2 = (const float*)d_in[6];
  const float* W3 = (const float*)d_in[7];
  const float* b3 = (const float*)d_in[8];
  const float* lW1 = (const float*)d_in[9];
  const float* lb1 = (const float*)d_in[10];
  const float* lW2 = (const float*)d_in[11];
  const float* lb2 = (const float*)d_in[12];

  int N = in_sizes[2];            // labels: [N,1]
  int E = in_sizes[1] / 2;        // edge_index: [2,E]
  const int* rows = ei;           // sources
  const int* cols = ei + E;       // targets (aggregation)

  int nb = (N + 255) / 256;
  int Npad = (N + 63) & ~63;

  // workspace layout (bf16 feature buffers)
  char* ws = (char*)d_ws;
  unsigned short* A   = (unsigned short*)ws;            // (h@W)*dinv  Npad*64 bf16
  unsigned short* H   = A + (size_t)Npad * 64;          // hidden      Npad*64 bf16
  unsigned short* Wt1 = H + (size_t)Npad * 64;          // 64*128
  unsigned short* Wt2 = Wt1 + 64 * 128;                 // 64*64
  unsigned short* Wt3 = Wt2 + 64 * 64;                  // 64*64
  float* dinv     = (float*)(Wt3 + 64 * 64);            // N
  int*   offsets  = (int*)(dinv + N);                   // N+1
  int*   deg      = offsets + N + 1;                    // N
  int*   cursor   = deg + N;                            // N
  int*   sorted   = cursor + N;                         // E
  int*   partials = sorted + E;                         // nb
  float* pmsum    = (float*)(partials + nb);            // 1

  float* loss = (float*)d_out;
  float* p    = (float*)d_out + 1;

  int gemmBlocks = Npad / 64;
  int aggBlocks  = (N + 3) / 4;
  int eBlocks    = (E + 255) / 256;

  // ---- weight transpose to bf16 (tiny) ----
  prep_wt<<<3, 256, 0, stream>>>(W1, W2, W3, Wt1, Wt2, Wt3);

  // ---- CSR build (once, reused for all 3 layers) ----
  hipMemsetAsync(deg, 0, (size_t)N * sizeof(int), stream);
  count_deg<<<eBlocks, 256, 0, stream>>>(cols, deg, pmsum, loss, E);
  label_sum_kernel<<<nb, 256, 0, stream>>>(labels, pmsum, N);
  scan_partials<<<nb, 256, 0, stream>>>(deg, partials, N);
  scan_block<<<1, 256, 0, stream>>>(partials, nb);
  scan_final<<<nb, 256, 0, stream>>>(deg, partials, offsets, cursor, dinv, N, E);
  for (int pass = 0; pass < 4; ++pass) {
    int lo = (int)((long)N * pass / 4);
    int hi = (int)((long)N * (pass + 1) / 4);
    fill_csr_range<<<eBlocks, 256, 0, stream>>>(rows, cols, cursor, sorted, E, lo, hi);
  }

  // ---- layer 1 (K=128, fp32 x converted in-flight) ----
  mfma_gemm<128, true><<<gemmBlocks, 256, 0, stream>>>(x, Wt1, dinv, A, N);
  aggregate<<<aggBlocks, 256, 0, stream>>>(A, offsets, sorted, dinv, b1, H, N);

  // ---- layer 2 (K=64, bf16) ----
  mfma_gemm<64, false><<<gemmBlocks, 256, 0, stream>>>(H, Wt2, dinv, A, N);
  aggregate<<<aggBlocks, 256, 0, stream>>>(A, offsets, sorted, dinv, b2, H, N);

  // ---- layer 3 (K=64, bf16) ----
  mfma_gemm<64, false><<<gemmBlocks, 256, 0, stream>>>(H, Wt3, dinv, A, N);
  aggregate<<<aggBlocks, 256, 0, stream>>>(A, offsets, sorted, dinv, b3, H, N);

  // ---- head + loss ----
  head_loss_kernel<<<nb, 256, 0, stream>>>(H, lW1, lb1, lW2, lb2, labels, pmsum, p, loss, N);
}

// Round 5
// 359.906 us; speedup vs baseline: 4.2714x; 1.3451x over previous
//
#include <hip/hip_runtime.h>
#include <cstdint>
#include <cstddef>

typedef __attribute__((ext_vector_type(8))) short short8;
typedef __attribute__((ext_vector_type(4))) float f32x4;

#define NBLK 512  // edge-chunk blocks for hist/scatter (must be pow2; logical idx uses >>9)

__device__ inline unsigned short f2bf(float f) {
  union { float f; unsigned int u; } x; x.f = f;
  unsigned int r = x.u + 0x7FFFu + ((x.u >> 16) & 1u);  // round-to-nearest-even
  return (unsigned short)(r >> 16);
}
__device__ inline float bf2f(unsigned short s) {
  union { unsigned int u; float f; } x; x.u = ((unsigned int)s) << 16;
  return x.f;
}

// ---------------- W -> W^T bf16 (tiny, once per call) ----------------

__global__ void prep_wt(const float* __restrict__ W1, const float* __restrict__ W2,
                        const float* __restrict__ W3, unsigned short* __restrict__ Wt1,
                        unsigned short* __restrict__ Wt2, unsigned short* __restrict__ Wt3) {
  const float* W; unsigned short* Wt; int K;
  if (blockIdx.x == 0)      { W = W1; Wt = Wt1; K = 128; }
  else if (blockIdx.x == 1) { W = W2; Wt = Wt2; K = 64; }
  else                      { W = W3; Wt = Wt3; K = 64; }
  int total = K * 64;
  for (int i = threadIdx.x; i < total; i += 256) {
    int n = i / K, k = i - n * K;      // Wt[n][k] = W[k][n]
    Wt[i] = f2bf(W[k * 64 + n]);
  }
}

// ---------------- P1: per-block bucket histogram (LDS atomics only) ----------------

__global__ __launch_bounds__(256) void hist_kernel(const int* __restrict__ cols,
                                                   int* __restrict__ histG,
                                                   float* __restrict__ pmsum,
                                                   float* __restrict__ loss,
                                                   int E, int NBUCK) {
  __shared__ int h[512];
  if (blockIdx.x == 0 && threadIdx.x == 0) { *pmsum = 0.f; *loss = 0.f; }
  for (int i = threadIdx.x; i < NBUCK; i += 256) h[i] = 0;
  __syncthreads();
  int chunk = (E + NBLK - 1) / NBLK;
  int s = blockIdx.x * chunk;
  int e = min(E, s + chunk);
  for (int i = s + threadIdx.x; i < e; i += 256) atomicAdd(&h[cols[i] >> 8], 1);
  __syncthreads();
  for (int i = threadIdx.x; i < NBUCK; i += 256)
    histG[blockIdx.x * NBUCK + i] = h[i];
}

// ---------------- P2: scan of NBUCK*NBLK counts, bucket-major logical order ----------------
// physical layout histG[blk][bucket]; logical L = bucket*NBLK + blk.

__global__ __launch_bounds__(256) void scan_partials_t(const int* __restrict__ histG,
                                                       int* __restrict__ partials,
                                                       int total, int NBUCK) {
  int i = blockIdx.x * 256 + threadIdx.x;
  int v = 0;
  if (i < total) {
    int bucket = i >> 9, blk = i & (NBLK - 1);
    v = histG[blk * NBUCK + bucket];
  }
#pragma unroll
  for (int o = 32; o > 0; o >>= 1) v += __shfl_down(v, o);
  __shared__ int s[4];
  if ((threadIdx.x & 63) == 0) s[threadIdx.x >> 6] = v;
  __syncthreads();
  if (threadIdx.x == 0) partials[blockIdx.x] = s[0] + s[1] + s[2] + s[3];
}

__global__ __launch_bounds__(256) void scan_block(int* __restrict__ partials, int nb) {
  __shared__ int tmp[256];
  __shared__ int carry;
  int tid = threadIdx.x;
  if (tid == 0) carry = 0;
  __syncthreads();
  for (int base = 0; base < nb; base += 256) {
    int i = base + tid;
    int v = (i < nb) ? partials[i] : 0;
    tmp[tid] = v;
    __syncthreads();
    int incl = v;
    for (int o = 1; o < 256; o <<= 1) {
      int t = (tid >= o) ? tmp[tid - o] : 0;
      __syncthreads();
      incl += t;
      tmp[tid] = incl;
      __syncthreads();
    }
    int total = tmp[255];
    int c = carry;
    if (i < nb) partials[i] = c + incl - v;  // exclusive
    __syncthreads();
    if (tid == 0) carry = c + total;
    __syncthreads();
  }
}

__global__ __launch_bounds__(256) void scan_final_t(const int* __restrict__ histG,
                                                    const int* __restrict__ partials,
                                                    int* __restrict__ scannedG,
                                                    int total, int NBUCK) {
  __shared__ int tmp[256];
  int tid = threadIdx.x;
  int i = blockIdx.x * 256 + tid;
  int bucket = i >> 9, blk = i & (NBLK - 1);
  int v = (i < total) ? histG[blk * NBUCK + bucket] : 0;
  tmp[tid] = v;
  __syncthreads();
  int incl = v;
  for (int o = 1; o < 256; o <<= 1) {
    int t = (tid >= o) ? tmp[tid - o] : 0;
    __syncthreads();
    incl += t;
    tmp[tid] = incl;
    __syncthreads();
  }
  if (i < total) scannedG[blk * NBUCK + bucket] = partials[blockIdx.x] + incl - v;
}

// ---------------- P3: bucket-partition scatter (LDS cursors, no global atomics) ----------------

__global__ __launch_bounds__(256) void scatter_kernel(const int* __restrict__ rows,
                                                      const int* __restrict__ cols,
                                                      const int* __restrict__ scannedG,
                                                      unsigned int* __restrict__ packed,
                                                      int E, int NBUCK) {
  __shared__ int cur[512];
  for (int i = threadIdx.x; i < NBUCK; i += 256)
    cur[i] = scannedG[blockIdx.x * NBUCK + i];
  __syncthreads();
  int chunk = (E + NBLK - 1) / NBLK;
  int s = blockIdx.x * chunk;
  int e = min(E, s + chunk);
  for (int i = s + threadIdx.x; i < e; i += 256) {
    int c = cols[i];
    int r = rows[i];
    int pos = atomicAdd(&cur[c >> 8], 1);
    packed[pos] = ((unsigned int)(c & 255) << 24) | (unsigned int)r;
  }
}

// ---------------- P4: per-bucket CSR finalize (offsets, dinv, sorted rows) ----------------
// one block per bucket; scatter confined to the bucket's ~16KB segment (L2-resident).

__global__ __launch_bounds__(256) void csr_finalize(const unsigned int* __restrict__ packed,
                                                    const int* __restrict__ scannedG,
                                                    int* __restrict__ sorted_src,
                                                    int* __restrict__ offsets,
                                                    float* __restrict__ dinv,
                                                    int N, int E, int NBUCK) {
  __shared__ int h[256];
  __shared__ int tmp[256];
  __shared__ int cur[256];
  int b = blockIdx.x;
  int tid = threadIdx.x;
  int base = scannedG[b];                               // blk=0 row = bucket starts
  int end = (b + 1 < NBUCK) ? scannedG[b + 1] : E;
  h[tid] = 0;
  __syncthreads();
  for (int i = base + tid; i < end; i += 256)
    atomicAdd(&h[packed[i] >> 24], 1);
  __syncthreads();
  int v = h[tid];
  tmp[tid] = v;
  __syncthreads();
  int incl = v;
  for (int o = 1; o < 256; o <<= 1) {
    int t = (tid >= o) ? tmp[tid - o] : 0;
    __syncthreads();
    incl += t;
    tmp[tid] = incl;
    __syncthreads();
  }
  int excl = incl - v;
  int node = b * 256 + tid;
  if (node < N) {
    offsets[node] = base + excl;
    dinv[node] = rsqrtf((float)(v + 1));  // +1 self loop
  }
  cur[tid] = base + excl;
  if (b == NBUCK - 1 && tid == 0) offsets[N] = E;
  __syncthreads();
  for (int i = base + tid; i < end; i += 256) {
    unsigned int p = packed[i];
    int pos = atomicAdd(&cur[p >> 24], 1);
    sorted_src[pos] = (int)(p & 0xFFFFFFu);
  }
}

// ---------------- MFMA GEMM: out_bf16[N,64] = (h[N,K] @ W[K,64]) * dinv[n] ----------------

template <int K, bool F32IN>
__global__ __launch_bounds__(256) void mfma_gemm(const void* __restrict__ hv,
                                                 const unsigned short* __restrict__ Wt,
                                                 const float* __restrict__ dinv,
                                                 unsigned short* __restrict__ out, int N) {
  __shared__ unsigned short tile[4][16 * 68];
  int w = threadIdx.x >> 6, lane = threadIdx.x & 63;
  int m = lane & 15, quad = lane >> 4;
  int m0 = blockIdx.x * 64 + w * 16;
  int rowA = m0 + m;
  bool rowOK = rowA < N;
  f32x4 acc[4] = {{0.f,0.f,0.f,0.f},{0.f,0.f,0.f,0.f},{0.f,0.f,0.f,0.f},{0.f,0.f,0.f,0.f}};
#pragma unroll
  for (int kc = 0; kc < K / 32; ++kc) {
    short8 a = {0, 0, 0, 0, 0, 0, 0, 0};
    if (rowOK) {
      if (F32IN) {
        const float* hp = (const float*)hv + (size_t)rowA * K + kc * 32 + quad * 8;
        float4 p0 = ((const float4*)hp)[0];
        float4 p1 = ((const float4*)hp)[1];
        a[0] = (short)f2bf(p0.x); a[1] = (short)f2bf(p0.y);
        a[2] = (short)f2bf(p0.z); a[3] = (short)f2bf(p0.w);
        a[4] = (short)f2bf(p1.x); a[5] = (short)f2bf(p1.y);
        a[6] = (short)f2bf(p1.z); a[7] = (short)f2bf(p1.w);
      } else {
        a = *(const short8*)((const unsigned short*)hv + (size_t)rowA * K + kc * 32 + quad * 8);
      }
    }
#pragma unroll
    for (int t = 0; t < 4; ++t) {
      short8 b = *(const short8*)(Wt + (size_t)(t * 16 + m) * K + kc * 32 + quad * 8);
      acc[t] = __builtin_amdgcn_mfma_f32_16x16x32_bf16(a, b, acc[t], 0, 0, 0);
    }
  }
  unsigned short* tw = tile[w];
#pragma unroll
  for (int r = 0; r < 4; ++r) {
    int row = quad * 4 + r;
    int gr = m0 + row;
    float dv = dinv[gr < N ? gr : 0];
#pragma unroll
    for (int t = 0; t < 4; ++t)
      tw[row * 68 + t * 16 + m] = f2bf(acc[t][r] * dv);
  }
#pragma unroll
  for (int p = 0; p < 4; ++p) {
    int row = p * 4 + (lane >> 4);
    int ch = lane & 15;
    int gr = m0 + row;
    if (gr < N) {
      uint2 v = *(const uint2*)(tw + row * 68 + ch * 4);
      *(uint2*)(out + (size_t)gr * 64 + ch * 4) = v;
    }
  }
}

// ---------------- fused gather-aggregate + self loop + bias + ReLU (bf16) ----------------

__global__ __launch_bounds__(256) void aggregate(const unsigned short* __restrict__ A,
                                                 const int* __restrict__ offsets,
                                                 const int* __restrict__ sorted_src,
                                                 const float* __restrict__ dinv,
                                                 const float* __restrict__ bias,
                                                 unsigned short* __restrict__ out, int N) {
  int c = blockIdx.x * 4 + (threadIdx.x >> 6);
  if (c >= N) return;
  int lane = threadIdx.x & 63;
  int g = lane >> 3;   // edge sub-slot 0..7
  int fi = lane & 7;   // 16B chunk of the 128B row
  int s = offsets[c], e = offsets[c + 1];
  float acc[8] = {0.f, 0.f, 0.f, 0.f, 0.f, 0.f, 0.f, 0.f};
  for (int base = s; base < e; base += 64) {
    int idx = base + lane;
    int r = (idx < e) ? sorted_src[idx] : 0;
    int cnt = e - base; if (cnt > 64) cnt = 64;
    int steps = (cnt + 7) >> 3;
    for (int t = 0; t < steps; ++t) {
      int jj = t * 8 + g;
      int rj = __shfl(r, jj);
      if (jj < cnt) {
        short8 v = *(const short8*)(A + (size_t)rj * 64 + fi * 8);
#pragma unroll
        for (int q = 0; q < 8; ++q) acc[q] += bf2f((unsigned short)v[q]);
      }
    }
  }
#pragma unroll
  for (int q = 0; q < 8; ++q) {
    acc[q] += __shfl_xor(acc[q], 8);
    acc[q] += __shfl_xor(acc[q], 16);
    acc[q] += __shfl_xor(acc[q], 32);
  }
  if (g == 0) {
    float dc = dinv[c];
    short8 sv = *(const short8*)(A + (size_t)c * 64 + fi * 8);
    short8 ov;
#pragma unroll
    for (int q = 0; q < 8; ++q) {
      float v = fmaf(acc[q] + bf2f((unsigned short)sv[q]), dc, bias[fi * 8 + q]);
      ov[q] = (short)f2bf(v > 0.f ? v : 0.f);
    }
    *(short8*)(out + (size_t)c * 64 + fi * 8) = ov;
  }
}

// ---------------- label mean partial sum ----------------

__global__ __launch_bounds__(256) void label_sum_kernel(const int* __restrict__ labels,
                                                        float* __restrict__ out, int N) {
  int i = blockIdx.x * 256 + threadIdx.x;
  float v = (i < N) ? (float)labels[i] : 0.f;
#pragma unroll
  for (int o = 32; o > 0; o >>= 1) v += __shfl_down(v, o);
  __shared__ float s[4];
  int lane = threadIdx.x & 63, w = threadIdx.x >> 6;
  if (lane == 0) s[w] = v;
  __syncthreads();
  if (threadIdx.x == 0) atomicAdd(out, s[0] + s[1] + s[2] + s[3]);
}

// ---------------- fused MLP head + sigmoid + weighted BCE loss (bf16 h) ----------------

__global__ __launch_bounds__(256) void head_loss_kernel(const unsigned short* __restrict__ h,
                                                        const float* __restrict__ lW1,
                                                        const float* __restrict__ lb1,
                                                        const float* __restrict__ lW2,
                                                        const float* __restrict__ lb2,
                                                        const int* __restrict__ labels,
                                                        const float* __restrict__ pmsum,
                                                        float* __restrict__ p,
                                                        float* __restrict__ loss, int N) {
  int n = blockIdx.x * 256 + threadIdx.x;
  float contrib = 0.f;
  if (n < N) {
    float acc[8];
#pragma unroll
    for (int j = 0; j < 8; ++j) acc[j] = lb1[j];
    const unsigned short* hr = h + (size_t)n * 64;
#pragma unroll
    for (int ch = 0; ch < 8; ++ch) {
      short8 hv8 = ((const short8*)hr)[ch];
#pragma unroll
      for (int q = 0; q < 8; ++q) {
        float v = bf2f((unsigned short)hv8[q]);
        int k = ch * 8 + q;
#pragma unroll
        for (int j = 0; j < 8; ++j) acc[j] = fmaf(v, lW1[k * 8 + j], acc[j]);
      }
    }
    float s = lb2[0];
#pragma unroll
    for (int j = 0; j < 8; ++j) {
      float a = acc[j] > 0.f ? acc[j] : 0.f;
      s = fmaf(a, lW2[j], s);
    }
    float pv = 1.0f / (1.0f + expf(-s));
    p[n] = pv;
    float pm = *pmsum / (float)N;
    float y = (float)labels[n];
    float w = y * (1.f - pm) + (1.f - y) * pm;
    float pc = fminf(fmaxf(pv, 1e-7f), 1.f - 1e-7f);
    float bce = -(y * logf(pc) + (1.f - y) * logf(1.f - pc));
    contrib = w * bce / (float)N;
  }
#pragma unroll
  for (int o = 32; o > 0; o >>= 1) contrib += __shfl_down(contrib, o);
  __shared__ float sh[4];
  int lane = threadIdx.x & 63, w = threadIdx.x >> 6;
  if (lane == 0) sh[w] = contrib;
  __syncthreads();
  if (threadIdx.x == 0) atomicAdd(loss, sh[0] + sh[1] + sh[2] + sh[3]);
}

// ---------------- launch ----------------

extern "C" void kernel_launch(void* const* d_in, const int* in_sizes, int n_in,
                              void* d_out, int out_size, void* d_ws, size_t ws_size,
                              hipStream_t stream) {
  const float* x      = (const float*)d_in[0];
  const int*   ei     = (const int*)d_in[1];
  const int*   labels = (const int*)d_in[2];
  const float* W1 = (const float*)d_in[3];
  const float* b1 = (const float*)d_in[4];
  const float* W2 = (const float*)d_in[5];
  const float* b2 = (const float*)d_in[6];
  const float* W3 = (const float*)d_in[7];
  const float* b3 = (const float*)d_in[8];
  const float* lW1 = (const float*)d_in[9];
  const float* lb1 = (const float*)d_in[10];
  const float* lW2 = (const float*)d_in[11];
  const float* lb2 = (const float*)d_in[12];

  int N = in_sizes[2];            // labels: [N,1]
  int E = in_sizes[1] / 2;        // edge_index: [2,E]
  const int* rows = ei;           // sources
  const int* cols = ei + E;       // targets (aggregation)

  int nb = (N + 255) / 256;
  int Npad = (N + 63) & ~63;
  int NBUCK = (N + 255) >> 8;               // 256-node buckets
  int totalH = NBUCK * NBLK;                // histogram entries
  int nb2 = (totalH + 255) / 256;

  // workspace layout
  char* ws = (char*)d_ws;
  unsigned short* A   = (unsigned short*)ws;            // (h@W)*dinv  Npad*64 bf16
  unsigned short* H   = A + (size_t)Npad * 64;          // hidden      Npad*64 bf16
  unsigned short* Wt1 = H + (size_t)Npad * 64;          // 64*128
  unsigned short* Wt2 = Wt1 + 64 * 128;                 // 64*64
  unsigned short* Wt3 = Wt2 + 64 * 64;                  // 64*64
  float* dinv     = (float*)(Wt3 + 64 * 64);            // N
  int*   offsets  = (int*)(dinv + N);                   // N+1
  int*   histG    = offsets + N + 1;                    // NBLK*NBUCK
  int*   scanned  = histG + totalH;                     // NBLK*NBUCK
  unsigned int* packed = (unsigned int*)(scanned + totalH);  // E
  int*   sorted   = (int*)(packed + E);                 // E
  int*   partials = sorted + E;                         // nb2
  float* pmsum    = (float*)(partials + nb2);           // 1

  float* loss = (float*)d_out;
  float* p    = (float*)d_out + 1;

  int gemmBlocks = Npad / 64;
  int aggBlocks  = (N + 3) / 4;

  // ---- weight transpose to bf16 (tiny) ----
  prep_wt<<<3, 256, 0, stream>>>(W1, W2, W3, Wt1, Wt2, Wt3);

  // ---- atomic-free CSR build ----
  hist_kernel<<<NBLK, 256, 0, stream>>>(cols, histG, pmsum, loss, E, NBUCK);
  label_sum_kernel<<<nb, 256, 0, stream>>>(labels, pmsum, N);
  scan_partials_t<<<nb2, 256, 0, stream>>>(histG, partials, totalH, NBUCK);
  scan_block<<<1, 256, 0, stream>>>(partials, nb2);
  scan_final_t<<<nb2, 256, 0, stream>>>(histG, partials, scanned, totalH, NBUCK);
  scatter_kernel<<<NBLK, 256, 0, stream>>>(rows, cols, scanned, packed, E, NBUCK);
  csr_finalize<<<NBUCK, 256, 0, stream>>>(packed, scanned, sorted, offsets, dinv, N, E, NBUCK);

  // ---- layer 1 (K=128, fp32 x converted in-flight) ----
  mfma_gemm<128, true><<<gemmBlocks, 256, 0, stream>>>(x, Wt1, dinv, A, N);
  aggregate<<<aggBlocks, 256, 0, stream>>>(A, offsets, sorted, dinv, b1, H, N);

  // ---- layer 2 (K=64, bf16) ----
  mfma_gemm<64, false><<<gemmBlocks, 256, 0, stream>>>(H, Wt2, dinv, A, N);
  aggregate<<<aggBlocks, 256, 0, stream>>>(A, offsets, sorted, dinv, b2, H, N);

  // ---- layer 3 (K=64, bf16) ----
  mfma_gemm<64, false><<<gemmBlocks, 256, 0, stream>>>(H, Wt3, dinv, A, N);
  aggregate<<<aggBlocks, 256, 0, stream>>>(A, offsets, sorted, dinv, b3, H, N);

  // ---- head + loss ----
  head_loss_kernel<<<nb, 256, 0, stream>>>(H, lW1, lb1, lW2, lb2, labels, pmsum, p, loss, N);
}